// Round 12
// baseline (365.418 us; speedup 1.0000x reference)
//
#include <hip/hip_runtime.h>
#include <math.h>

// Problem constants
#define BBATCH 4
#define LSEQ   2048
#define DMODEL 256
#define DINNER 512
#define DSTATE 16
#define DTRANK 16
#define MROWS  (BBATCH * LSEQ)   // 8192
#define NCHUNK 64
#define LCHUNK (LSEQ / NCHUNK)   // 32

typedef unsigned short u16;
typedef __attribute__((ext_vector_type(8))) short bf16x8;   // 8 bf16 in 4 VGPRs
typedef __attribute__((ext_vector_type(4))) float f32x4;

// Workspace layout (float units). ≈108 MB total (proven OK).
#define OFF_HBF    ((size_t)0)            // 8192*256 bf16
#define OFF_HCONV  ((size_t)1048576)
#define OFF_XIN    ((size_t)3145728)      // 8192*512 bf16 (half the region)
#define OFF_Z      ((size_t)7340032)      // 8192*512 bf16
#define OFF_XC     ((size_t)11534336)     // fp32
#define OFF_DELTA  ((size_t)15728640)     // fp32
#define OFF_XDBL   ((size_t)19922944)
#define OFF_YBF    ((size_t)20316160)
#define OFF_AAGG   ((size_t)22413312)
#define OFF_BAGG   ((size_t)24510464)
#define OFF_HINIT  OFF_AAGG               // scan2 reads Aagg[idx] before writing Hinit[idx]
#define OFF_WTINBF ((size_t)26607616)
#define OFF_WTCVBF ((size_t)26738688)
#define OFF_WTOUTBF ((size_t)26836992)
#define OFF_WTX    ((size_t)26902528)
#define OFF_WTDT   ((size_t)26927104)

__device__ __forceinline__ float silu_f(float v) {
  return v / (1.0f + __expf(-v));
}
__device__ __forceinline__ u16 f2bf(float f) {   // RNE float->bf16
  unsigned u = __float_as_uint(f);
  return (u16)((u + 0x7FFFu + ((u >> 16) & 1u)) >> 16);
}
__device__ __forceinline__ float bf2f(u16 v) {
  return __uint_as_float(((unsigned)v) << 16);
}

// ---------------- weight repack (+ fp32->bf16 casts) -------------------------
__global__ __launch_bounds__(256) void k_repack(
    const float* __restrict__ inw, const float* __restrict__ convw,
    const float* __restrict__ xw, const float* __restrict__ dtw,
    const float* __restrict__ ow, float* __restrict__ ws) {
  int idx = blockIdx.x * 256 + threadIdx.x;
  u16* win  = (u16*)(ws + OFF_WTINBF);
  u16* wcv  = (u16*)(ws + OFF_WTCVBF);
  u16* wout = (u16*)(ws + OFF_WTOUTBF);
  float* wx  = ws + OFF_WTX;
  float* wdt = ws + OFF_WTDT;
  if (idx < 262144) {            // Wt_in_bf[n][k] = inw[n][k]
    win[idx] = f2bf(inw[idx]);
    return;
  }
  int i2 = idx - 262144;
  if (i2 < 196608) {             // Wt_conv_bf[o][kk*256+i] = convw[(o*256+i)*3+kk]
    int o = i2 / 768, r = i2 - o * 768;
    int kk = r >> 8, i = r & 255;
    wcv[i2] = f2bf(convw[(o * 256 + i) * 3 + kk]);
    return;
  }
  int i3 = i2 - 196608;
  if (i3 < 131072) {             // Wt_out_bf[n][k] = ow[n][k]
    wout[i3] = f2bf(ow[i3]);
    return;
  }
  int i4 = i3 - 131072;
  if (i4 < 24576) {              // Wt_x[k*48+n] = xw[n*512+k]
    int k = i4 / 48, n = i4 - k * 48;
    wx[i4] = xw[n * 512 + k];
    return;
  }
  int i5 = i4 - 24576;
  if (i5 < 8192) {               // Wt_dt[r*512+n] = dtw[n*16+r]
    int r = i5 >> 9, n = i5 & 511;
    wdt[i5] = dtw[n * 16 + r];
  }
}

// ---------------- layernorm: one wave per row of 256; bf16 output ------------
__global__ __launch_bounds__(256) void k_layernorm(
    const float* __restrict__ x, const float* __restrict__ w,
    const float* __restrict__ b, u16* __restrict__ hb) {
  int wave = threadIdx.x >> 6;
  int lane = threadIdx.x & 63;
  int row  = blockIdx.x * 4 + wave;
  const float4* xr = reinterpret_cast<const float4*>(x + (size_t)row * 256);
  float4 v = xr[lane];
  float s  = v.x + v.y + v.z + v.w;
  float sq = v.x*v.x + v.y*v.y + v.z*v.z + v.w*v.w;
  #pragma unroll
  for (int o = 32; o >= 1; o >>= 1) { s += __shfl_xor(s, o); sq += __shfl_xor(sq, o); }
  float mu  = s * (1.0f / 256.0f);
  float var = sq * (1.0f / 256.0f) - mu * mu;
  float rs  = rsqrtf(var + 1e-5f);
  float4 wv = reinterpret_cast<const float4*>(w)[lane];
  float4 bv = reinterpret_cast<const float4*>(b)[lane];
  ushort4 o4;
  o4.x = f2bf((v.x - mu) * rs * wv.x + bv.x);
  o4.y = f2bf((v.y - mu) * rs * wv.y + bv.y);
  o4.z = f2bf((v.z - mu) * rs * wv.z + bv.z);
  o4.w = f2bf((v.w - mu) * rs * wv.w + bv.w);
  reinterpret_cast<ushort4*>(hb + (size_t)row * 256)[lane] = o4;
}

// ================= bf16 MFMA GEMMs =========================================
// LDS rows padded to 72 bf16 (144 B stride -> 2-way bank alias, free per m136).
// A frag: row=lane&15, k=(lane>>4)*8+i. B n-major. C/D: col=lane&15,
// row=(lane>>4)*4+reg (m89-verified).

// in_proj: 64x128 tile, 4 waves (1x4, per-wave 64x32 = 4x2 frags), BK=64.
// Writes xin/z as bf16.
__global__ __launch_bounds__(256) void k_bgemm_inproj(
    const u16* __restrict__ Abf, const u16* __restrict__ Bbf,
    u16* __restrict__ xin, u16* __restrict__ z) {
  __shared__ __align__(16) u16 As[64 * 72];
  __shared__ __align__(16) u16 Bs[128 * 72];
  int tid = threadIdx.x;
  int m0 = blockIdx.x * 64, n0 = blockIdx.y * 128;
  int lane = tid & 63, wid = tid >> 6;
  int wc = wid * 32;                       // wave's 32-col slice of 128
  int l15 = lane & 15, lk = (lane >> 4) * 8;
  int r0 = tid >> 3, kc = (tid & 7) * 8;
  f32x4 acc[4][2] = {};
  for (int k0 = 0; k0 < 256; k0 += 64) {
    *(bf16x8*)&As[r0 * 72 + kc] =
        *(const bf16x8*)&Abf[(size_t)(m0 + r0) * 256 + k0 + kc];
    *(bf16x8*)&As[(r0 + 32) * 72 + kc] =
        *(const bf16x8*)&Abf[(size_t)(m0 + r0 + 32) * 256 + k0 + kc];
    #pragma unroll
    for (int rr = 0; rr < 4; ++rr)
      *(bf16x8*)&Bs[(r0 + rr * 32) * 72 + kc] =
          *(const bf16x8*)&Bbf[(size_t)(n0 + r0 + rr * 32) * 256 + k0 + kc];
    __syncthreads();
    #pragma unroll
    for (int kk = 0; kk < 64; kk += 32) {
      bf16x8 b0 = *(const bf16x8*)&Bs[(wc + l15) * 72 + kk + lk];
      bf16x8 b1 = *(const bf16x8*)&Bs[(wc + 16 + l15) * 72 + kk + lk];
      #pragma unroll
      for (int q = 0; q < 4; ++q) {
        bf16x8 a = *(const bf16x8*)&As[(q * 16 + l15) * 72 + kk + lk];
        acc[q][0] = __builtin_amdgcn_mfma_f32_16x16x32_bf16(a, b0, acc[q][0], 0, 0, 0);
        acc[q][1] = __builtin_amdgcn_mfma_f32_16x16x32_bf16(a, b1, acc[q][1], 0, 0, 0);
      }
    }
    __syncthreads();
  }
  u16* dst = (blockIdx.y < 4) ? xin : z;
  int nb = n0 & 511;
  int rsub = (lane >> 4) * 4;
  #pragma unroll
  for (int q = 0; q < 4; ++q)
    #pragma unroll
    for (int ni = 0; ni < 2; ++ni) {
      int gc = nb + wc + ni * 16 + l15;
      #pragma unroll
      for (int r = 0; r < 4; ++r)
        dst[(size_t)(m0 + q * 16 + rsub + r) * 512 + gc] = f2bf(acc[q][ni][r]);
    }
}

// conv branch: 64x64 tile, GELU epilogue
__global__ __launch_bounds__(256) void k_bgemm_conv(
    const u16* __restrict__ hbf, const u16* __restrict__ Bbf,
    const float* __restrict__ cb, float* __restrict__ hconv) {
  __shared__ __align__(16) u16 As[64 * 72];
  __shared__ __align__(16) u16 Bs[64 * 72];
  int tid = threadIdx.x;
  int m0 = blockIdx.x * 64, n0 = blockIdx.y * 64;
  int bidx = m0 >> 11, t0 = m0 & 2047;
  int lane = tid & 63, wid = tid >> 6;
  int wr = (wid >> 1) * 32, wc = (wid & 1) * 32;
  int l15 = lane & 15, lk = (lane >> 4) * 8;
  int r0 = tid >> 3, kc = (tid & 7) * 8;
  f32x4 acc[2][2] = {};
  for (int k0 = 0; k0 < 768; k0 += 64) {
    int kkc = k0 >> 8;
    int i0  = (k0 & 255) + kc;
    int t1  = t0 + r0 - 2 + kkc;
    bf16x8 av0 = {0, 0, 0, 0, 0, 0, 0, 0};
    if (t1 >= 0)
      av0 = *(const bf16x8*)&hbf[(size_t)((bidx << 11) + t1) * 256 + i0];
    bf16x8 av1 =
        *(const bf16x8*)&hbf[(size_t)((bidx << 11) + t1 + 32) * 256 + i0];
    *(bf16x8*)&As[r0 * 72 + kc] = av0;
    *(bf16x8*)&As[(r0 + 32) * 72 + kc] = av1;
    *(bf16x8*)&Bs[r0 * 72 + kc] =
        *(const bf16x8*)&Bbf[(size_t)(n0 + r0) * 768 + k0 + kc];
    *(bf16x8*)&Bs[(r0 + 32) * 72 + kc] =
        *(const bf16x8*)&Bbf[(size_t)(n0 + r0 + 32) * 768 + k0 + kc];
    __syncthreads();
    #pragma unroll
    for (int kk = 0; kk < 64; kk += 32) {
      bf16x8 a0 = *(const bf16x8*)&As[(wr + l15) * 72 + kk + lk];
      bf16x8 a1 = *(const bf16x8*)&As[(wr + 16 + l15) * 72 + kk + lk];
      bf16x8 b0 = *(const bf16x8*)&Bs[(wc + l15) * 72 + kk + lk];
      bf16x8 b1 = *(const bf16x8*)&Bs[(wc + 16 + l15) * 72 + kk + lk];
      acc[0][0] = __builtin_amdgcn_mfma_f32_16x16x32_bf16(a0, b0, acc[0][0], 0, 0, 0);
      acc[0][1] = __builtin_amdgcn_mfma_f32_16x16x32_bf16(a0, b1, acc[0][1], 0, 0, 0);
      acc[1][0] = __builtin_amdgcn_mfma_f32_16x16x32_bf16(a1, b0, acc[1][0], 0, 0, 0);
      acc[1][1] = __builtin_amdgcn_mfma_f32_16x16x32_bf16(a1, b1, acc[1][1], 0, 0, 0);
    }
    __syncthreads();
  }
  int rowb = m0 + wr + (lane >> 4) * 4;
  #pragma unroll
  for (int mi = 0; mi < 2; ++mi)
    #pragma unroll
    for (int ni = 0; ni < 2; ++ni) {
      int gc = n0 + wc + ni * 16 + l15;
      float bias = cb[gc];
      #pragma unroll
      for (int r = 0; r < 4; ++r) {
        float v = acc[mi][ni][r] + bias;
        float g = 0.5f * v * (1.0f + erff(v * 0.70710678118654752440f));
        hconv[(size_t)(rowb + mi * 16 + r) * 256 + gc] = g;
      }
    }
}

// out_proj + combine: out = x + 0.5*(y_bf @ Wt_out_bf^T) + 0.5*hconv
__global__ __launch_bounds__(256) void k_bgemm_outproj(
    const u16* __restrict__ Abf, const u16* __restrict__ Bbf,
    const float* __restrict__ x, const float* __restrict__ hconv,
    float* __restrict__ out) {
  __shared__ __align__(16) u16 As[64 * 72];
  __shared__ __align__(16) u16 Bs[64 * 72];
  int tid = threadIdx.x;
  int m0 = blockIdx.x * 64, n0 = blockIdx.y * 64;
  int lane = tid & 63, wid = tid >> 6;
  int wr = (wid >> 1) * 32, wc = (wid & 1) * 32;
  int l15 = lane & 15, lk = (lane >> 4) * 8;
  int r0 = tid >> 3, kc = (tid & 7) * 8;
  f32x4 acc[2][2] = {};
  for (int k0 = 0; k0 < 512; k0 += 64) {
    *(bf16x8*)&As[r0 * 72 + kc] =
        *(const bf16x8*)&Abf[(size_t)(m0 + r0) * 512 + k0 + kc];
    *(bf16x8*)&As[(r0 + 32) * 72 + kc] =
        *(const bf16x8*)&Abf[(size_t)(m0 + r0 + 32) * 512 + k0 + kc];
    *(bf16x8*)&Bs[r0 * 72 + kc] =
        *(const bf16x8*)&Bbf[(size_t)(n0 + r0) * 512 + k0 + kc];
    *(bf16x8*)&Bs[(r0 + 32) * 72 + kc] =
        *(const bf16x8*)&Bbf[(size_t)(n0 + r0 + 32) * 512 + k0 + kc];
    __syncthreads();
    #pragma unroll
    for (int kk = 0; kk < 64; kk += 32) {
      bf16x8 a0 = *(const bf16x8*)&As[(wr + l15) * 72 + kk + lk];
      bf16x8 a1 = *(const bf16x8*)&As[(wr + 16 + l15) * 72 + kk + lk];
      bf16x8 b0 = *(const bf16x8*)&Bs[(wc + l15) * 72 + kk + lk];
      bf16x8 b1 = *(const bf16x8*)&Bs[(wc + 16 + l15) * 72 + kk + lk];
      acc[0][0] = __builtin_amdgcn_mfma_f32_16x16x32_bf16(a0, b0, acc[0][0], 0, 0, 0);
      acc[0][1] = __builtin_amdgcn_mfma_f32_16x16x32_bf16(a0, b1, acc[0][1], 0, 0, 0);
      acc[1][0] = __builtin_amdgcn_mfma_f32_16x16x32_bf16(a1, b0, acc[1][0], 0, 0, 0);
      acc[1][1] = __builtin_amdgcn_mfma_f32_16x16x32_bf16(a1, b1, acc[1][1], 0, 0, 0);
    }
    __syncthreads();
  }
  int rowb = m0 + wr + (lane >> 4) * 4;
  #pragma unroll
  for (int mi = 0; mi < 2; ++mi)
    #pragma unroll
    for (int ni = 0; ni < 2; ++ni) {
      int gc = n0 + wc + ni * 16 + l15;
      #pragma unroll
      for (int r = 0; r < 4; ++r) {
        size_t off = (size_t)(rowb + mi * 16 + r) * 256 + gc;
        out[off] = x[off] + 0.5f * acc[mi][ni][r] + 0.5f * hconv[off];
      }
    }
}

// x_proj re-tiled: 16-row x 48-col tile, 512 blocks. Same fp32 math and
// k-ascending accumulation order as before (bitwise-compatible output).
// Thread = (row rr = tid>>4, col group cg = tid&15 -> cols 3*cg..3*cg+2).
__global__ __launch_bounds__(256) void k_gemm_xproj(
    const float* __restrict__ A, const float* __restrict__ Bt,
    float* __restrict__ C) {
  __shared__ float As[16][17];
  __shared__ float Bs[16][52];
  int tid = threadIdx.x;
  int m0 = blockIdx.x * 16;
  int rr = tid >> 4, cg = tid & 15;
  float acc0 = 0.f, acc1 = 0.f, acc2 = 0.f;
  for (int k0 = 0; k0 < 512; k0 += 16) {
    As[rr][cg] = A[(size_t)(m0 + rr) * 512 + k0 + cg];
    int e0 = tid;
    Bs[e0 / 48][e0 % 48] = Bt[(size_t)(k0 + e0 / 48) * 48 + (e0 % 48)];
    int e1 = tid + 256;
    Bs[e1 / 48][e1 % 48] = Bt[(size_t)(k0 + e1 / 48) * 48 + (e1 % 48)];
    int e2 = tid + 512;
    if (e2 < 768)
      Bs[e2 / 48][e2 % 48] = Bt[(size_t)(k0 + e2 / 48) * 48 + (e2 % 48)];
    __syncthreads();
    #pragma unroll
    for (int kt = 0; kt < 16; ++kt) {
      float a = As[rr][kt];
      acc0 += a * Bs[kt][cg * 3 + 0];
      acc1 += a * Bs[kt][cg * 3 + 1];
      acc2 += a * Bs[kt][cg * 3 + 2];
    }
    __syncthreads();
  }
  size_t o = (size_t)(m0 + rr) * 48 + cg * 3;
  C[o + 0] = acc0;
  C[o + 1] = acc1;
  C[o + 2] = acc2;
}

// dt_proj re-tiled: 32 rows/block, 256 blocks. Wdt column pair in registers
// (read ONCE per thread: L2 traffic 268 MB -> 8 MB). Same accumulation order.
__global__ __launch_bounds__(256) void k_dtproj(
    const float* __restrict__ xdbl, const float* __restrict__ Wdt,
    const float* __restrict__ db, float* __restrict__ delta) {
  __shared__ float dts[32][17];
  int tid = threadIdx.x;
  int m0 = blockIdx.x * 32;
  {
    int rr = tid >> 4, cc = tid & 15;
    dts[rr][cc]      = xdbl[(size_t)(m0 + rr) * 48 + cc];
    dts[rr + 16][cc] = xdbl[(size_t)(m0 + rr + 16) * 48 + cc];
  }
  __syncthreads();
  float wv0[16], wv1[16];
  #pragma unroll
  for (int r = 0; r < 16; ++r) {
    wv0[r] = Wdt[r * 512 + tid];
    wv1[r] = Wdt[r * 512 + tid + 256];
  }
  float b0 = db[tid], b1 = db[tid + 256];
  for (int m = 0; m < 32; ++m) {
    float a0 = b0, a1 = b1;
    #pragma unroll
    for (int r = 0; r < 16; ++r) {
      float d = dts[m][r];
      a0 += d * wv0[r];
      a1 += d * wv1[r];
    }
    delta[(size_t)(m0 + m) * 512 + tid]       = (a0 > 20.0f) ? a0 : log1pf(__expf(a0));
    delta[(size_t)(m0 + m) * 512 + tid + 256] = (a1 > 20.0f) ? a1 : log1pf(__expf(a1));
  }
}

// ---------------- depthwise causal conv (DCONV=4) + SiLU; bf16 input ---------
__global__ __launch_bounds__(256) void k_dwconv(
    const u16* __restrict__ xin, const float* __restrict__ cw,
    const float* __restrict__ cb, float* __restrict__ xc) {
  int idx = blockIdx.x * 256 + threadIdx.x;
  int di = idx & 511;
  int m  = idx >> 9;
  int t  = m & 2047;
  float w0 = cw[di * 4 + 0], w1 = cw[di * 4 + 1];
  float w2 = cw[di * 4 + 2], w3 = cw[di * 4 + 3];
  const u16* base = xin + (size_t)m * 512 + di;
  float acc = cb[di] + w3 * bf2f(base[0]);
  if (t >= 1) acc += w2 * bf2f(base[-512]);
  if (t >= 2) acc += w1 * bf2f(base[-1024]);
  if (t >= 3) acc += w0 * bf2f(base[-1536]);
  xc[(size_t)m * 512 + di] = silu_f(acc);
}

// ---------------- chunked scan: thread-per-(b,chunk,di), 16 states in regs --
__global__ __launch_bounds__(256) void k_scan1(
    const float* __restrict__ delta, const float* __restrict__ xdbl,
    const float* __restrict__ xc, const float* __restrict__ Alog,
    float* __restrict__ Aagg, float* __restrict__ Bagg) {
  int di = ((blockIdx.x & 1) << 8) | threadIdx.x;
  int c  = (blockIdx.x >> 1) & 63;
  int b  = blockIdx.x >> 7;
  float nA[16];
  #pragma unroll
  for (int q = 0; q < 4; ++q) {
    float4 v = *reinterpret_cast<const float4*>(Alog + (size_t)di * 16 + q * 4);
    nA[q*4+0] = -__expf(v.x); nA[q*4+1] = -__expf(v.y);
    nA[q*4+2] = -__expf(v.z); nA[q*4+3] = -__expf(v.w);
  }
  float ap[16], bacc[16];
  #pragma unroll
  for (int s = 0; s < 16; ++s) { ap[s] = 1.0f; bacc[s] = 0.0f; }
  int row0 = b * 2048 + c * LCHUNK;
  const float* dp = delta + (size_t)row0 * 512 + di;
  const float* xp = xc    + (size_t)row0 * 512 + di;
  const float* Bp = xdbl  + (size_t)row0 * 48 + 16;
  #pragma unroll 2
  for (int t = 0; t < LCHUNK; ++t) {
    float dv = dp[t * 512];
    float u  = dv * xp[t * 512];
    #pragma unroll
    for (int s = 0; s < 16; ++s) {
      float e = __expf(dv * nA[s]);
      ap[s]   *= e;
      bacc[s]  = e * bacc[s] + u * Bp[t * 48 + s];
    }
  }
  size_t base = ((size_t)((b * 64 + c) * 16)) * 512 + di;
  #pragma unroll
  for (int s = 0; s < 16; ++s) {
    Aagg[base + (size_t)s * 512] = ap[s];
    Bagg[base + (size_t)s * 512] = bacc[s];
  }
}

__global__ __launch_bounds__(256) void k_scan2(
    const float* __restrict__ Aagg, const float* __restrict__ Bagg,
    float* __restrict__ Hinit) {
  int g  = blockIdx.x * 256 + threadIdx.x;
  int di = g & 511, s = (g >> 9) & 15, b = g >> 13;
  float h = 0.0f;
  for (int c = 0; c < NCHUNK; ++c) {
    size_t idx = ((size_t)((b * 64 + c) * 16 + s)) * 512 + di;
    float a = Aagg[idx], bb = Bagg[idx];
    Hinit[idx] = h;
    h = a * h + bb;
  }
}

// pass 3: re-scan; fused y = (scan + xc*D) * silu(z); bf16 z input, bf16 y out
__global__ __launch_bounds__(256) void k_scan3(
    const float* __restrict__ delta, const float* __restrict__ xdbl,
    const float* __restrict__ xc, const u16* __restrict__ z,
    const float* __restrict__ Alog, const float* __restrict__ Dp,
    const float* __restrict__ Hinit, u16* __restrict__ y) {
  int di = ((blockIdx.x & 1) << 8) | threadIdx.x;
  int c  = (blockIdx.x >> 1) & 63;
  int b  = blockIdx.x >> 7;
  float nA[16];
  #pragma unroll
  for (int q = 0; q < 4; ++q) {
    float4 v = *reinterpret_cast<const float4*>(Alog + (size_t)di * 16 + q * 4);
    nA[q*4+0] = -__expf(v.x); nA[q*4+1] = -__expf(v.y);
    nA[q*4+2] = -__expf(v.z); nA[q*4+3] = -__expf(v.w);
  }
  float h[16];
  size_t hb = ((size_t)((b * 64 + c) * 16)) * 512 + di;
  #pragma unroll
  for (int s = 0; s < 16; ++s) h[s] = Hinit[hb + (size_t)s * 512];
  float Dv = Dp[di];
  int row0 = b * 2048 + c * LCHUNK;
  const float* dp = delta + (size_t)row0 * 512 + di;
  const float* xp = xc    + (size_t)row0 * 512 + di;
  const u16*   zp = z     + (size_t)row0 * 512 + di;
  const float* Bp = xdbl  + (size_t)row0 * 48 + 16;
  const float* Cp = xdbl  + (size_t)row0 * 48 + 32;
  u16* yp         = y     + (size_t)row0 * 512 + di;
  #pragma unroll 2
  for (int t = 0; t < LCHUNK; ++t) {
    float dv  = dp[t * 512];
    float xcv = xp[t * 512];
    float u   = dv * xcv;
    float yv  = 0.0f;
    #pragma unroll
    for (int s = 0; s < 16; ++s) {
      float e = __expf(dv * nA[s]);
      h[s] = e * h[s] + u * Bp[t * 48 + s];
      yv  += h[s] * Cp[t * 48 + s];
    }
    yv += xcv * Dv;
    float zv = bf2f(zp[t * 512]);
    yp[t * 512] = f2bf(yv * silu_f(zv));
  }
}

// ---------------- host launcher ---------------------------------------------
extern "C" void kernel_launch(void* const* d_in, const int* in_sizes, int n_in,
                              void* d_out, int out_size, void* d_ws, size_t ws_size,
                              hipStream_t stream) {
  const float* x     = (const float*)d_in[0];
  const float* lnw   = (const float*)d_in[1];
  const float* lnb   = (const float*)d_in[2];
  const float* convw = (const float*)d_in[3];
  const float* convb = (const float*)d_in[4];
  const float* inw   = (const float*)d_in[5];
  const float* c1w   = (const float*)d_in[6];
  const float* c1b   = (const float*)d_in[7];
  const float* xw    = (const float*)d_in[8];
  const float* dtw   = (const float*)d_in[9];
  const float* dtb   = (const float*)d_in[10];
  const float* alog  = (const float*)d_in[11];
  const float* Dp    = (const float*)d_in[12];
  const float* ow    = (const float*)d_in[13];
  float* ws  = (float*)d_ws;
  float* out = (float*)d_out;

  u16* hbf     = (u16*)(ws + OFF_HBF);
  float* hconv = ws + OFF_HCONV;
  u16* xinbf   = (u16*)(ws + OFF_XIN);
  u16* zbf     = (u16*)(ws + OFF_Z);
  float* xc    = ws + OFF_XC;
  float* delta = ws + OFF_DELTA;
  float* xdbl  = ws + OFF_XDBL;
  u16* ybf     = (u16*)(ws + OFF_YBF);
  float* Aagg  = ws + OFF_AAGG;
  float* Bagg  = ws + OFF_BAGG;
  float* Hinit = ws + OFF_HINIT;
  u16* winbf   = (u16*)(ws + OFF_WTINBF);
  u16* wcvbf   = (u16*)(ws + OFF_WTCVBF);
  u16* woutbf  = (u16*)(ws + OFF_WTOUTBF);
  float* Wtx   = ws + OFF_WTX;
  float* Wtdt  = ws + OFF_WTDT;

  k_repack<<<2432, 256, 0, stream>>>(inw, convw, xw, dtw, ow, ws);
  k_layernorm<<<2048, 256, 0, stream>>>(x, lnw, lnb, hbf);
  k_bgemm_conv<<<dim3(128, 4), 256, 0, stream>>>(hbf, wcvbf, convb, hconv);
  k_bgemm_inproj<<<dim3(128, 8), 256, 0, stream>>>(hbf, winbf, xinbf, zbf);
  k_dwconv<<<16384, 256, 0, stream>>>(xinbf, c1w, c1b, xc);
  k_gemm_xproj<<<512, 256, 0, stream>>>(xc, Wtx, xdbl);
  k_dtproj<<<256, 256, 0, stream>>>(xdbl, Wtdt, dtb, delta);
  k_scan1<<<512, 256, 0, stream>>>(delta, xdbl, xc, alog, Aagg, Bagg);
  k_scan2<<<128, 256, 0, stream>>>(Aagg, Bagg, Hinit);
  k_scan3<<<512, 256, 0, stream>>>(delta, xdbl, xc, zbf, alog, Dp, Hinit, ybf);
  k_bgemm_outproj<<<dim3(128, 4), 256, 0, stream>>>(ybf, woutbf, x, hconv, out);
}

// Round 13
// 237.944 us; speedup vs baseline: 1.5357x; 1.5357x over previous
//
#include <hip/hip_runtime.h>
#include <math.h>

// Problem constants
#define BBATCH 4
#define LSEQ   2048
#define DMODEL 256
#define DINNER 512
#define DSTATE 16
#define DTRANK 16
#define MROWS  (BBATCH * LSEQ)   // 8192
#define NCHUNK 64
#define LCHUNK (LSEQ / NCHUNK)   // 32

typedef unsigned short u16;
typedef __attribute__((ext_vector_type(8))) short bf16x8;   // 8 bf16 in 4 VGPRs
typedef __attribute__((ext_vector_type(4))) float f32x4;

// Workspace layout (float units). ≈108 MB total (proven OK).
#define OFF_HBF    ((size_t)0)            // 8192*256 bf16
#define OFF_HCONV  ((size_t)1048576)
#define OFF_XIN    ((size_t)3145728)      // 8192*512 bf16 (first half of region)
#define OFF_XPART  ((size_t)5242880)      // 4*8192*48 fp32 partials (xproj K-split)
#define OFF_Z      ((size_t)7340032)      // 8192*512 bf16
#define OFF_XC     ((size_t)11534336)     // fp32
#define OFF_DELTA  ((size_t)15728640)     // fp32
#define OFF_XDBL   ((size_t)19922944)
#define OFF_YBF    ((size_t)20316160)
#define OFF_AAGG   ((size_t)22413312)
#define OFF_BAGG   ((size_t)24510464)
#define OFF_HINIT  OFF_AAGG               // scan2 reads Aagg[idx] before writing Hinit[idx]
#define OFF_WTINBF ((size_t)26607616)
#define OFF_WTCVBF ((size_t)26738688)
#define OFF_WTOUTBF ((size_t)26836992)
#define OFF_WTX    ((size_t)26902528)
#define OFF_WTDT   ((size_t)26927104)

__device__ __forceinline__ float silu_f(float v) {
  return v / (1.0f + __expf(-v));
}
__device__ __forceinline__ u16 f2bf(float f) {   // RNE float->bf16
  unsigned u = __float_as_uint(f);
  return (u16)((u + 0x7FFFu + ((u >> 16) & 1u)) >> 16);
}
__device__ __forceinline__ float bf2f(u16 v) {
  return __uint_as_float(((unsigned)v) << 16);
}

// ---------------- weight repack (+ fp32->bf16 casts) -------------------------
__global__ __launch_bounds__(256) void k_repack(
    const float* __restrict__ inw, const float* __restrict__ convw,
    const float* __restrict__ xw, const float* __restrict__ dtw,
    const float* __restrict__ ow, float* __restrict__ ws) {
  int idx = blockIdx.x * 256 + threadIdx.x;
  u16* win  = (u16*)(ws + OFF_WTINBF);
  u16* wcv  = (u16*)(ws + OFF_WTCVBF);
  u16* wout = (u16*)(ws + OFF_WTOUTBF);
  float* wx  = ws + OFF_WTX;
  float* wdt = ws + OFF_WTDT;
  if (idx < 262144) {            // Wt_in_bf[n][k] = inw[n][k]
    win[idx] = f2bf(inw[idx]);
    return;
  }
  int i2 = idx - 262144;
  if (i2 < 196608) {             // Wt_conv_bf[o][kk*256+i] = convw[(o*256+i)*3+kk]
    int o = i2 / 768, r = i2 - o * 768;
    int kk = r >> 8, i = r & 255;
    wcv[i2] = f2bf(convw[(o * 256 + i) * 3 + kk]);
    return;
  }
  int i3 = i2 - 196608;
  if (i3 < 131072) {             // Wt_out_bf[n][k] = ow[n][k]
    wout[i3] = f2bf(ow[i3]);
    return;
  }
  int i4 = i3 - 131072;
  if (i4 < 24576) {              // Wt_x[k*48+n] = xw[n*512+k]
    int k = i4 / 48, n = i4 - k * 48;
    wx[i4] = xw[n * 512 + k];
    return;
  }
  int i5 = i4 - 24576;
  if (i5 < 8192) {               // Wt_dt[r*512+n] = dtw[n*16+r]
    int r = i5 >> 9, n = i5 & 511;
    wdt[i5] = dtw[n * 16 + r];
  }
}

// ---------------- layernorm: one wave per row of 256; bf16 output ------------
__global__ __launch_bounds__(256) void k_layernorm(
    const float* __restrict__ x, const float* __restrict__ w,
    const float* __restrict__ b, u16* __restrict__ hb) {
  int wave = threadIdx.x >> 6;
  int lane = threadIdx.x & 63;
  int row  = blockIdx.x * 4 + wave;
  const float4* xr = reinterpret_cast<const float4*>(x + (size_t)row * 256);
  float4 v = xr[lane];
  float s  = v.x + v.y + v.z + v.w;
  float sq = v.x*v.x + v.y*v.y + v.z*v.z + v.w*v.w;
  #pragma unroll
  for (int o = 32; o >= 1; o >>= 1) { s += __shfl_xor(s, o); sq += __shfl_xor(sq, o); }
  float mu  = s * (1.0f / 256.0f);
  float var = sq * (1.0f / 256.0f) - mu * mu;
  float rs  = rsqrtf(var + 1e-5f);
  float4 wv = reinterpret_cast<const float4*>(w)[lane];
  float4 bv = reinterpret_cast<const float4*>(b)[lane];
  ushort4 o4;
  o4.x = f2bf((v.x - mu) * rs * wv.x + bv.x);
  o4.y = f2bf((v.y - mu) * rs * wv.y + bv.y);
  o4.z = f2bf((v.z - mu) * rs * wv.z + bv.z);
  o4.w = f2bf((v.w - mu) * rs * wv.w + bv.w);
  reinterpret_cast<ushort4*>(hb + (size_t)row * 256)[lane] = o4;
}

// ================= bf16 MFMA GEMMs =========================================
// LDS rows padded to 72 bf16 (144 B stride -> 2-way bank alias, free per m136).
// A frag: row=lane&15, k=(lane>>4)*8+i. B n-major. C/D: col=lane&15,
// row=(lane>>4)*4+reg (m89-verified).

// in_proj: 64x128 tile, 4 waves (1x4, per-wave 64x32 = 4x2 frags), BK=64.
// Writes xin/z as bf16.
__global__ __launch_bounds__(256) void k_bgemm_inproj(
    const u16* __restrict__ Abf, const u16* __restrict__ Bbf,
    u16* __restrict__ xin, u16* __restrict__ z) {
  __shared__ __align__(16) u16 As[64 * 72];
  __shared__ __align__(16) u16 Bs[128 * 72];
  int tid = threadIdx.x;
  int m0 = blockIdx.x * 64, n0 = blockIdx.y * 128;
  int lane = tid & 63, wid = tid >> 6;
  int wc = wid * 32;                       // wave's 32-col slice of 128
  int l15 = lane & 15, lk = (lane >> 4) * 8;
  int r0 = tid >> 3, kc = (tid & 7) * 8;
  f32x4 acc[4][2] = {};
  for (int k0 = 0; k0 < 256; k0 += 64) {
    *(bf16x8*)&As[r0 * 72 + kc] =
        *(const bf16x8*)&Abf[(size_t)(m0 + r0) * 256 + k0 + kc];
    *(bf16x8*)&As[(r0 + 32) * 72 + kc] =
        *(const bf16x8*)&Abf[(size_t)(m0 + r0 + 32) * 256 + k0 + kc];
    #pragma unroll
    for (int rr = 0; rr < 4; ++rr)
      *(bf16x8*)&Bs[(r0 + rr * 32) * 72 + kc] =
          *(const bf16x8*)&Bbf[(size_t)(n0 + r0 + rr * 32) * 256 + k0 + kc];
    __syncthreads();
    #pragma unroll
    for (int kk = 0; kk < 64; kk += 32) {
      bf16x8 b0 = *(const bf16x8*)&Bs[(wc + l15) * 72 + kk + lk];
      bf16x8 b1 = *(const bf16x8*)&Bs[(wc + 16 + l15) * 72 + kk + lk];
      #pragma unroll
      for (int q = 0; q < 4; ++q) {
        bf16x8 a = *(const bf16x8*)&As[(q * 16 + l15) * 72 + kk + lk];
        acc[q][0] = __builtin_amdgcn_mfma_f32_16x16x32_bf16(a, b0, acc[q][0], 0, 0, 0);
        acc[q][1] = __builtin_amdgcn_mfma_f32_16x16x32_bf16(a, b1, acc[q][1], 0, 0, 0);
      }
    }
    __syncthreads();
  }
  u16* dst = (blockIdx.y < 4) ? xin : z;
  int nb = n0 & 511;
  int rsub = (lane >> 4) * 4;
  #pragma unroll
  for (int q = 0; q < 4; ++q)
    #pragma unroll
    for (int ni = 0; ni < 2; ++ni) {
      int gc = nb + wc + ni * 16 + l15;
      #pragma unroll
      for (int r = 0; r < 4; ++r)
        dst[(size_t)(m0 + q * 16 + rsub + r) * 512 + gc] = f2bf(acc[q][ni][r]);
    }
}

// conv branch: 64x64 tile, GELU epilogue
__global__ __launch_bounds__(256) void k_bgemm_conv(
    const u16* __restrict__ hbf, const u16* __restrict__ Bbf,
    const float* __restrict__ cb, float* __restrict__ hconv) {
  __shared__ __align__(16) u16 As[64 * 72];
  __shared__ __align__(16) u16 Bs[64 * 72];
  int tid = threadIdx.x;
  int m0 = blockIdx.x * 64, n0 = blockIdx.y * 64;
  int bidx = m0 >> 11, t0 = m0 & 2047;
  int lane = tid & 63, wid = tid >> 6;
  int wr = (wid >> 1) * 32, wc = (wid & 1) * 32;
  int l15 = lane & 15, lk = (lane >> 4) * 8;
  int r0 = tid >> 3, kc = (tid & 7) * 8;
  f32x4 acc[2][2] = {};
  for (int k0 = 0; k0 < 768; k0 += 64) {
    int kkc = k0 >> 8;
    int i0  = (k0 & 255) + kc;
    int t1  = t0 + r0 - 2 + kkc;
    bf16x8 av0 = {0, 0, 0, 0, 0, 0, 0, 0};
    if (t1 >= 0)
      av0 = *(const bf16x8*)&hbf[(size_t)((bidx << 11) + t1) * 256 + i0];
    bf16x8 av1 =
        *(const bf16x8*)&hbf[(size_t)((bidx << 11) + t1 + 32) * 256 + i0];
    *(bf16x8*)&As[r0 * 72 + kc] = av0;
    *(bf16x8*)&As[(r0 + 32) * 72 + kc] = av1;
    *(bf16x8*)&Bs[r0 * 72 + kc] =
        *(const bf16x8*)&Bbf[(size_t)(n0 + r0) * 768 + k0 + kc];
    *(bf16x8*)&Bs[(r0 + 32) * 72 + kc] =
        *(const bf16x8*)&Bbf[(size_t)(n0 + r0 + 32) * 768 + k0 + kc];
    __syncthreads();
    #pragma unroll
    for (int kk = 0; kk < 64; kk += 32) {
      bf16x8 a0 = *(const bf16x8*)&As[(wr + l15) * 72 + kk + lk];
      bf16x8 a1 = *(const bf16x8*)&As[(wr + 16 + l15) * 72 + kk + lk];
      bf16x8 b0 = *(const bf16x8*)&Bs[(wc + l15) * 72 + kk + lk];
      bf16x8 b1 = *(const bf16x8*)&Bs[(wc + 16 + l15) * 72 + kk + lk];
      acc[0][0] = __builtin_amdgcn_mfma_f32_16x16x32_bf16(a0, b0, acc[0][0], 0, 0, 0);
      acc[0][1] = __builtin_amdgcn_mfma_f32_16x16x32_bf16(a0, b1, acc[0][1], 0, 0, 0);
      acc[1][0] = __builtin_amdgcn_mfma_f32_16x16x32_bf16(a1, b0, acc[1][0], 0, 0, 0);
      acc[1][1] = __builtin_amdgcn_mfma_f32_16x16x32_bf16(a1, b1, acc[1][1], 0, 0, 0);
    }
    __syncthreads();
  }
  int rowb = m0 + wr + (lane >> 4) * 4;
  #pragma unroll
  for (int mi = 0; mi < 2; ++mi)
    #pragma unroll
    for (int ni = 0; ni < 2; ++ni) {
      int gc = n0 + wc + ni * 16 + l15;
      float bias = cb[gc];
      #pragma unroll
      for (int r = 0; r < 4; ++r) {
        float v = acc[mi][ni][r] + bias;
        float g = 0.5f * v * (1.0f + erff(v * 0.70710678118654752440f));
        hconv[(size_t)(rowb + mi * 16 + r) * 256 + gc] = g;
      }
    }
}

// out_proj + combine: out = x + 0.5*(y_bf @ Wt_out_bf^T) + 0.5*hconv
__global__ __launch_bounds__(256) void k_bgemm_outproj(
    const u16* __restrict__ Abf, const u16* __restrict__ Bbf,
    const float* __restrict__ x, const float* __restrict__ hconv,
    float* __restrict__ out) {
  __shared__ __align__(16) u16 As[64 * 72];
  __shared__ __align__(16) u16 Bs[64 * 72];
  int tid = threadIdx.x;
  int m0 = blockIdx.x * 64, n0 = blockIdx.y * 64;
  int lane = tid & 63, wid = tid >> 6;
  int wr = (wid >> 1) * 32, wc = (wid & 1) * 32;
  int l15 = lane & 15, lk = (lane >> 4) * 8;
  int r0 = tid >> 3, kc = (tid & 7) * 8;
  f32x4 acc[2][2] = {};
  for (int k0 = 0; k0 < 512; k0 += 64) {
    *(bf16x8*)&As[r0 * 72 + kc] =
        *(const bf16x8*)&Abf[(size_t)(m0 + r0) * 512 + k0 + kc];
    *(bf16x8*)&As[(r0 + 32) * 72 + kc] =
        *(const bf16x8*)&Abf[(size_t)(m0 + r0 + 32) * 512 + k0 + kc];
    *(bf16x8*)&Bs[r0 * 72 + kc] =
        *(const bf16x8*)&Bbf[(size_t)(n0 + r0) * 512 + k0 + kc];
    *(bf16x8*)&Bs[(r0 + 32) * 72 + kc] =
        *(const bf16x8*)&Bbf[(size_t)(n0 + r0 + 32) * 512 + k0 + kc];
    __syncthreads();
    #pragma unroll
    for (int kk = 0; kk < 64; kk += 32) {
      bf16x8 a0 = *(const bf16x8*)&As[(wr + l15) * 72 + kk + lk];
      bf16x8 a1 = *(const bf16x8*)&As[(wr + 16 + l15) * 72 + kk + lk];
      bf16x8 b0 = *(const bf16x8*)&Bs[(wc + l15) * 72 + kk + lk];
      bf16x8 b1 = *(const bf16x8*)&Bs[(wc + 16 + l15) * 72 + kk + lk];
      acc[0][0] = __builtin_amdgcn_mfma_f32_16x16x32_bf16(a0, b0, acc[0][0], 0, 0, 0);
      acc[0][1] = __builtin_amdgcn_mfma_f32_16x16x32_bf16(a0, b1, acc[0][1], 0, 0, 0);
      acc[1][0] = __builtin_amdgcn_mfma_f32_16x16x32_bf16(a1, b0, acc[1][0], 0, 0, 0);
      acc[1][1] = __builtin_amdgcn_mfma_f32_16x16x32_bf16(a1, b1, acc[1][1], 0, 0, 0);
    }
    __syncthreads();
  }
  int rowb = m0 + wr + (lane >> 4) * 4;
  #pragma unroll
  for (int mi = 0; mi < 2; ++mi)
    #pragma unroll
    for (int ni = 0; ni < 2; ++ni) {
      int gc = n0 + wc + ni * 16 + l15;
      #pragma unroll
      for (int r = 0; r < 4; ++r) {
        size_t off = (size_t)(rowb + mi * 16 + r) * 256 + gc;
        out[off] = x[off] + 0.5f * acc[mi][ni][r] + 0.5f * hconv[off];
      }
    }
}

// x_proj K-split phase 1: Cpart[kc][8192][48] over K-chunk [kc*128, kc*128+128).
// Body identical to the R5-measured 64x48 tile (same per-chunk accumulation
// order); grid (128 m-tiles, 4 k-chunks) = 512 blocks.
__global__ __launch_bounds__(256) void k_xproj_part(
    const float* __restrict__ A, const float* __restrict__ Bt,
    float* __restrict__ Cpart) {
  __shared__ float As[16][68];
  __shared__ float Bs[16][68];
  int tid = threadIdx.x;
  int m0 = blockIdx.x * 64;
  int kc = blockIdx.y;                      // 0..3
  int ar = tid >> 2, ac = (tid & 3) * 4;
  int br = tid >> 4, bc = (tid & 15) * 4;
  int tx = tid & 15, ty = tid >> 4;
  float acc[4][4] = {};
  for (int k0 = kc * 128; k0 < kc * 128 + 128; k0 += 16) {
    float4 av = *reinterpret_cast<const float4*>(A + (size_t)(m0 + ar) * 512 + k0 + ac);
    As[ac + 0][ar] = av.x; As[ac + 1][ar] = av.y;
    As[ac + 2][ar] = av.z; As[ac + 3][ar] = av.w;
    float4 bv = make_float4(0.f, 0.f, 0.f, 0.f);
    if (bc < 48)
      bv = *reinterpret_cast<const float4*>(Bt + (size_t)(k0 + br) * 48 + bc);
    *reinterpret_cast<float4*>(&Bs[br][bc]) = bv;
    __syncthreads();
    #pragma unroll
    for (int kt = 0; kt < 16; ++kt) {
      float4 a = *reinterpret_cast<const float4*>(&As[kt][ty * 4]);
      float4 b = *reinterpret_cast<const float4*>(&Bs[kt][tx * 4]);
      acc[0][0]+=a.x*b.x; acc[0][1]+=a.x*b.y; acc[0][2]+=a.x*b.z; acc[0][3]+=a.x*b.w;
      acc[1][0]+=a.y*b.x; acc[1][1]+=a.y*b.y; acc[1][2]+=a.y*b.z; acc[1][3]+=a.y*b.w;
      acc[2][0]+=a.z*b.x; acc[2][1]+=a.z*b.y; acc[2][2]+=a.z*b.z; acc[2][3]+=a.z*b.w;
      acc[3][0]+=a.w*b.x; acc[3][1]+=a.w*b.y; acc[3][2]+=a.w*b.z; acc[3][3]+=a.w*b.w;
    }
    __syncthreads();
  }
  float* C = Cpart + (size_t)kc * (MROWS * 48);
  if (tx < 12) {
    #pragma unroll
    for (int i = 0; i < 4; ++i) {
      float4 cv = make_float4(acc[i][0], acc[i][1], acc[i][2], acc[i][3]);
      *reinterpret_cast<float4*>(C + (size_t)(m0 + ty * 4 + i) * 48 + tx * 4) = cv;
    }
  }
}

// x_proj K-split phase 2: xdbl = sum of 4 partials (k-chunk-ascending order)
__global__ __launch_bounds__(256) void k_xproj_sum(
    const float* __restrict__ Cpart, float* __restrict__ C) {
  int idx = blockIdx.x * 256 + threadIdx.x;   // < 393216
  const size_t S = (size_t)MROWS * 48;
  C[idx] = ((Cpart[idx] + Cpart[S + idx]) + Cpart[2 * S + idx]) + Cpart[3 * S + idx];
}

// dt_proj: 2048 blocks x 4 rows (8 blocks/CU -> latency hidden), Wdt column
// pair in registers (64 MB L2 total). Same r-ascending accumulation order.
__global__ __launch_bounds__(256) void k_dtproj(
    const float* __restrict__ xdbl, const float* __restrict__ Wdt,
    const float* __restrict__ db, float* __restrict__ delta) {
  __shared__ float dts[4][17];
  int tid = threadIdx.x;
  int m0 = blockIdx.x * 4;
  if (tid < 64) {
    int rr = tid >> 4, cc = tid & 15;
    dts[rr][cc] = xdbl[(size_t)(m0 + rr) * 48 + cc];
  }
  __syncthreads();
  float wv0[16], wv1[16];
  #pragma unroll
  for (int r = 0; r < 16; ++r) {
    wv0[r] = Wdt[r * 512 + tid];
    wv1[r] = Wdt[r * 512 + tid + 256];
  }
  float b0 = db[tid], b1 = db[tid + 256];
  #pragma unroll
  for (int m = 0; m < 4; ++m) {
    float a0 = b0, a1 = b1;
    #pragma unroll
    for (int r = 0; r < 16; ++r) {
      float d = dts[m][r];
      a0 += d * wv0[r];
      a1 += d * wv1[r];
    }
    delta[(size_t)(m0 + m) * 512 + tid]       = (a0 > 20.0f) ? a0 : log1pf(__expf(a0));
    delta[(size_t)(m0 + m) * 512 + tid + 256] = (a1 > 20.0f) ? a1 : log1pf(__expf(a1));
  }
}

// ---------------- depthwise causal conv (DCONV=4) + SiLU; bf16 input ---------
__global__ __launch_bounds__(256) void k_dwconv(
    const u16* __restrict__ xin, const float* __restrict__ cw,
    const float* __restrict__ cb, float* __restrict__ xc) {
  int idx = blockIdx.x * 256 + threadIdx.x;
  int di = idx & 511;
  int m  = idx >> 9;
  int t  = m & 2047;
  float w0 = cw[di * 4 + 0], w1 = cw[di * 4 + 1];
  float w2 = cw[di * 4 + 2], w3 = cw[di * 4 + 3];
  const u16* base = xin + (size_t)m * 512 + di;
  float acc = cb[di] + w3 * bf2f(base[0]);
  if (t >= 1) acc += w2 * bf2f(base[-512]);
  if (t >= 2) acc += w1 * bf2f(base[-1024]);
  if (t >= 3) acc += w0 * bf2f(base[-1536]);
  xc[(size_t)m * 512 + di] = silu_f(acc);
}

// ---------------- chunked scan: thread-per-(b,chunk,di), 16 states in regs --
__global__ __launch_bounds__(256) void k_scan1(
    const float* __restrict__ delta, const float* __restrict__ xdbl,
    const float* __restrict__ xc, const float* __restrict__ Alog,
    float* __restrict__ Aagg, float* __restrict__ Bagg) {
  int di = ((blockIdx.x & 1) << 8) | threadIdx.x;
  int c  = (blockIdx.x >> 1) & 63;
  int b  = blockIdx.x >> 7;
  float nA[16];
  #pragma unroll
  for (int q = 0; q < 4; ++q) {
    float4 v = *reinterpret_cast<const float4*>(Alog + (size_t)di * 16 + q * 4);
    nA[q*4+0] = -__expf(v.x); nA[q*4+1] = -__expf(v.y);
    nA[q*4+2] = -__expf(v.z); nA[q*4+3] = -__expf(v.w);
  }
  float ap[16], bacc[16];
  #pragma unroll
  for (int s = 0; s < 16; ++s) { ap[s] = 1.0f; bacc[s] = 0.0f; }
  int row0 = b * 2048 + c * LCHUNK;
  const float* dp = delta + (size_t)row0 * 512 + di;
  const float* xp = xc    + (size_t)row0 * 512 + di;
  const float* Bp = xdbl  + (size_t)row0 * 48 + 16;
  #pragma unroll 2
  for (int t = 0; t < LCHUNK; ++t) {
    float dv = dp[t * 512];
    float u  = dv * xp[t * 512];
    #pragma unroll
    for (int s = 0; s < 16; ++s) {
      float e = __expf(dv * nA[s]);
      ap[s]   *= e;
      bacc[s]  = e * bacc[s] + u * Bp[t * 48 + s];
    }
  }
  size_t base = ((size_t)((b * 64 + c) * 16)) * 512 + di;
  #pragma unroll
  for (int s = 0; s < 16; ++s) {
    Aagg[base + (size_t)s * 512] = ap[s];
    Bagg[base + (size_t)s * 512] = bacc[s];
  }
}

__global__ __launch_bounds__(256) void k_scan2(
    const float* __restrict__ Aagg, const float* __restrict__ Bagg,
    float* __restrict__ Hinit) {
  int g  = blockIdx.x * 256 + threadIdx.x;
  int di = g & 511, s = (g >> 9) & 15, b = g >> 13;
  float h = 0.0f;
  for (int c = 0; c < NCHUNK; ++c) {
    size_t idx = ((size_t)((b * 64 + c) * 16 + s)) * 512 + di;
    float a = Aagg[idx], bb = Bagg[idx];
    Hinit[idx] = h;
    h = a * h + bb;
  }
}

// pass 3: re-scan; fused y = (scan + xc*D) * silu(z); bf16 z input, bf16 y out
__global__ __launch_bounds__(256) void k_scan3(
    const float* __restrict__ delta, const float* __restrict__ xdbl,
    const float* __restrict__ xc, const u16* __restrict__ z,
    const float* __restrict__ Alog, const float* __restrict__ Dp,
    const float* __restrict__ Hinit, u16* __restrict__ y) {
  int di = ((blockIdx.x & 1) << 8) | threadIdx.x;
  int c  = (blockIdx.x >> 1) & 63;
  int b  = blockIdx.x >> 7;
  float nA[16];
  #pragma unroll
  for (int q = 0; q < 4; ++q) {
    float4 v = *reinterpret_cast<const float4*>(Alog + (size_t)di * 16 + q * 4);
    nA[q*4+0] = -__expf(v.x); nA[q*4+1] = -__expf(v.y);
    nA[q*4+2] = -__expf(v.z); nA[q*4+3] = -__expf(v.w);
  }
  float h[16];
  size_t hb = ((size_t)((b * 64 + c) * 16)) * 512 + di;
  #pragma unroll
  for (int s = 0; s < 16; ++s) h[s] = Hinit[hb + (size_t)s * 512];
  float Dv = Dp[di];
  int row0 = b * 2048 + c * LCHUNK;
  const float* dp = delta + (size_t)row0 * 512 + di;
  const float* xp = xc    + (size_t)row0 * 512 + di;
  const u16*   zp = z     + (size_t)row0 * 512 + di;
  const float* Bp = xdbl  + (size_t)row0 * 48 + 16;
  const float* Cp = xdbl  + (size_t)row0 * 48 + 32;
  u16* yp         = y     + (size_t)row0 * 512 + di;
  #pragma unroll 2
  for (int t = 0; t < LCHUNK; ++t) {
    float dv  = dp[t * 512];
    float xcv = xp[t * 512];
    float u   = dv * xcv;
    float yv  = 0.0f;
    #pragma unroll
    for (int s = 0; s < 16; ++s) {
      float e = __expf(dv * nA[s]);
      h[s] = e * h[s] + u * Bp[t * 48 + s];
      yv  += h[s] * Cp[t * 48 + s];
    }
    yv += xcv * Dv;
    float zv = bf2f(zp[t * 512]);
    yp[t * 512] = f2bf(yv * silu_f(zv));
  }
}

// ---------------- host launcher ---------------------------------------------
extern "C" void kernel_launch(void* const* d_in, const int* in_sizes, int n_in,
                              void* d_out, int out_size, void* d_ws, size_t ws_size,
                              hipStream_t stream) {
  const float* x     = (const float*)d_in[0];
  const float* lnw   = (const float*)d_in[1];
  const float* lnb   = (const float*)d_in[2];
  const float* convw = (const float*)d_in[3];
  const float* convb = (const float*)d_in[4];
  const float* inw   = (const float*)d_in[5];
  const float* c1w   = (const float*)d_in[6];
  const float* c1b   = (const float*)d_in[7];
  const float* xw    = (const float*)d_in[8];
  const float* dtw   = (const float*)d_in[9];
  const float* dtb   = (const float*)d_in[10];
  const float* alog  = (const float*)d_in[11];
  const float* Dp    = (const float*)d_in[12];
  const float* ow    = (const float*)d_in[13];
  float* ws  = (float*)d_ws;
  float* out = (float*)d_out;

  u16* hbf     = (u16*)(ws + OFF_HBF);
  float* hconv = ws + OFF_HCONV;
  u16* xinbf   = (u16*)(ws + OFF_XIN);
  float* xpart = ws + OFF_XPART;
  u16* zbf     = (u16*)(ws + OFF_Z);
  float* xc    = ws + OFF_XC;
  float* delta = ws + OFF_DELTA;
  float* xdbl  = ws + OFF_XDBL;
  u16* ybf     = (u16*)(ws + OFF_YBF);
  float* Aagg  = ws + OFF_AAGG;
  float* Bagg  = ws + OFF_BAGG;
  float* Hinit = ws + OFF_HINIT;
  u16* winbf   = (u16*)(ws + OFF_WTINBF);
  u16* wcvbf   = (u16*)(ws + OFF_WTCVBF);
  u16* woutbf  = (u16*)(ws + OFF_WTOUTBF);
  float* Wtx   = ws + OFF_WTX;
  float* Wtdt  = ws + OFF_WTDT;

  k_repack<<<2432, 256, 0, stream>>>(inw, convw, xw, dtw, ow, ws);
  k_layernorm<<<2048, 256, 0, stream>>>(x, lnw, lnb, hbf);
  k_bgemm_conv<<<dim3(128, 4), 256, 0, stream>>>(hbf, wcvbf, convb, hconv);
  k_bgemm_inproj<<<dim3(128, 8), 256, 0, stream>>>(hbf, winbf, xinbf, zbf);
  k_dwconv<<<16384, 256, 0, stream>>>(xinbf, c1w, c1b, xc);
  k_xproj_part<<<dim3(128, 4), 256, 0, stream>>>(xc, Wtx, xpart);
  k_xproj_sum<<<1536, 256, 0, stream>>>(xpart, xdbl);
  k_dtproj<<<2048, 256, 0, stream>>>(xdbl, Wtdt, dtb, delta);
  k_scan1<<<512, 256, 0, stream>>>(delta, xdbl, xc, alog, Aagg, Bagg);
  k_scan2<<<128, 256, 0, stream>>>(Aagg, Bagg, Hinit);
  k_scan3<<<512, 256, 0, stream>>>(delta, xdbl, xc, zbf, alog, Dp, Hinit, ybf);
  k_bgemm_outproj<<<dim3(128, 4), 256, 0, stream>>>(ybf, woutbf, x, hconv, out);
}

// Round 14
// 218.901 us; speedup vs baseline: 1.6693x; 1.0870x over previous
//
#include <hip/hip_runtime.h>
#include <math.h>

// Problem constants
#define BBATCH 4
#define LSEQ   2048
#define DMODEL 256
#define DINNER 512
#define DSTATE 16
#define DTRANK 16
#define MROWS  (BBATCH * LSEQ)   // 8192
#define NCHUNK 64
#define LCHUNK (LSEQ / NCHUNK)   // 32

typedef unsigned short u16;
typedef __attribute__((ext_vector_type(8))) short bf16x8;   // 8 bf16 in 4 VGPRs
typedef __attribute__((ext_vector_type(4))) float f32x4;

// Workspace layout (float units). ≈108 MB total (proven OK).
#define OFF_HBF    ((size_t)0)            // 8192*256 bf16
#define OFF_HCONV  ((size_t)1048576)
#define OFF_XIN    ((size_t)3145728)      // 8192*512 bf16 (first half of region)
#define OFF_XPART  ((size_t)5242880)      // 4*8192*48 fp32 partials (xproj K-split)
#define OFF_Z      ((size_t)7340032)      // 8192*512 bf16
#define OFF_XC     ((size_t)11534336)     // fp32
#define OFF_DELTA  ((size_t)15728640)     // fp32
#define OFF_XDBL   ((size_t)19922944)
#define OFF_YBF    ((size_t)20316160)
#define OFF_AAGG   ((size_t)22413312)
#define OFF_BAGG   ((size_t)24510464)
#define OFF_HINIT  OFF_AAGG               // scan2 reads Aagg[idx] before writing Hinit[idx]
#define OFF_WTINBF ((size_t)26607616)
#define OFF_WTCVBF ((size_t)26738688)
#define OFF_WTOUTBF ((size_t)26836992)
#define OFF_WTX    ((size_t)26902528)
#define OFF_WTDT   ((size_t)26927104)

__device__ __forceinline__ float silu_f(float v) {
  return v / (1.0f + __expf(-v));
}
__device__ __forceinline__ u16 f2bf(float f) {   // RNE float->bf16
  unsigned u = __float_as_uint(f);
  return (u16)((u + 0x7FFFu + ((u >> 16) & 1u)) >> 16);
}
__device__ __forceinline__ float bf2f(u16 v) {
  return __uint_as_float(((unsigned)v) << 16);
}

// ---------------- fused layernorm + weight repack (independent work) ---------
// blocks 0..2047: layernorm (4 rows each, bf16 out). blocks 2048..4479: repack.
__global__ __launch_bounds__(256) void k_ln_repack(
    const float* __restrict__ x, const float* __restrict__ lnw,
    const float* __restrict__ lnb, u16* __restrict__ hb,
    const float* __restrict__ inw, const float* __restrict__ convw,
    const float* __restrict__ xw, const float* __restrict__ dtw,
    const float* __restrict__ ow, float* __restrict__ ws) {
  if (blockIdx.x < 2048) {
    int wave = threadIdx.x >> 6;
    int lane = threadIdx.x & 63;
    int row  = blockIdx.x * 4 + wave;
    const float4* xr = reinterpret_cast<const float4*>(x + (size_t)row * 256);
    float4 v = xr[lane];
    float s  = v.x + v.y + v.z + v.w;
    float sq = v.x*v.x + v.y*v.y + v.z*v.z + v.w*v.w;
    #pragma unroll
    for (int o = 32; o >= 1; o >>= 1) { s += __shfl_xor(s, o); sq += __shfl_xor(sq, o); }
    float mu  = s * (1.0f / 256.0f);
    float var = sq * (1.0f / 256.0f) - mu * mu;
    float rs  = rsqrtf(var + 1e-5f);
    float4 wv = reinterpret_cast<const float4*>(lnw)[lane];
    float4 bv = reinterpret_cast<const float4*>(lnb)[lane];
    ushort4 o4;
    o4.x = f2bf((v.x - mu) * rs * wv.x + bv.x);
    o4.y = f2bf((v.y - mu) * rs * wv.y + bv.y);
    o4.z = f2bf((v.z - mu) * rs * wv.z + bv.z);
    o4.w = f2bf((v.w - mu) * rs * wv.w + bv.w);
    reinterpret_cast<ushort4*>(hb + (size_t)row * 256)[lane] = o4;
    return;
  }
  int idx = (blockIdx.x - 2048) * 256 + threadIdx.x;
  u16* win  = (u16*)(ws + OFF_WTINBF);
  u16* wcv  = (u16*)(ws + OFF_WTCVBF);
  u16* wout = (u16*)(ws + OFF_WTOUTBF);
  float* wx  = ws + OFF_WTX;
  float* wdt = ws + OFF_WTDT;
  if (idx < 262144) {            // Wt_in_bf[n][k] = inw[n][k]
    win[idx] = f2bf(inw[idx]);
    return;
  }
  int i2 = idx - 262144;
  if (i2 < 196608) {             // Wt_conv_bf[o][kk*256+i] = convw[(o*256+i)*3+kk]
    int o = i2 / 768, r = i2 - o * 768;
    int kk = r >> 8, i = r & 255;
    wcv[i2] = f2bf(convw[(o * 256 + i) * 3 + kk]);
    return;
  }
  int i3 = i2 - 196608;
  if (i3 < 131072) {             // Wt_out_bf[n][k] = ow[n][k]
    wout[i3] = f2bf(ow[i3]);
    return;
  }
  int i4 = i3 - 131072;
  if (i4 < 24576) {              // Wt_x[k*48+n] = xw[n*512+k]
    int k = i4 / 48, n = i4 - k * 48;
    wx[i4] = xw[n * 512 + k];
    return;
  }
  int i5 = i4 - 24576;
  if (i5 < 8192) {               // Wt_dt[r*512+n] = dtw[n*16+r]
    int r = i5 >> 9, n = i5 & 511;
    wdt[i5] = dtw[n * 16 + r];
  }
}

// ================= bf16 MFMA GEMMs =========================================
// LDS rows padded to 72 bf16 (144 B stride -> 2-way bank alias, free per m136).
// A frag: row=lane&15, k=(lane>>4)*8+i. B n-major. C/D: col=lane&15,
// row=(lane>>4)*4+reg (m89-verified).

// Fused conv-GEMM + in_proj-GEMM (both consume hbf only).
// blocks 0..511: conv 64x64 tile (m=blk&127, n=blk>>7).
// blocks 512..1535: in_proj 64x128 tile (bid=blk-512: m=bid&127, n=bid>>7).
__global__ __launch_bounds__(256) void k_bgemm_both(
    const u16* __restrict__ hbf, const u16* __restrict__ Bcv,
    const float* __restrict__ cb, float* __restrict__ hconv,
    const u16* __restrict__ Bin, u16* __restrict__ xin, u16* __restrict__ z) {
  __shared__ __align__(16) u16 As[64 * 72];
  __shared__ __align__(16) u16 Bs[128 * 72];   // conv uses first 64*72
  int blk = blockIdx.x;
  int tid = threadIdx.x;
  int lane = tid & 63, wid = tid >> 6;
  int l15 = lane & 15, lk = (lane >> 4) * 8;
  int r0 = tid >> 3, kc = (tid & 7) * 8;
  if (blk < 512) {
    // ---- conv branch: A = im2col(hbf) [8192,768], GELU epilogue ----
    int m0 = (blk & 127) * 64, n0 = (blk >> 7) * 64;
    int bidx = m0 >> 11, t0 = m0 & 2047;
    int wr = (wid >> 1) * 32, wc = (wid & 1) * 32;
    f32x4 acc[2][2] = {};
    for (int k0 = 0; k0 < 768; k0 += 64) {
      int kkc = k0 >> 8;
      int i0  = (k0 & 255) + kc;
      int t1  = t0 + r0 - 2 + kkc;
      bf16x8 av0 = {0, 0, 0, 0, 0, 0, 0, 0};
      if (t1 >= 0)
        av0 = *(const bf16x8*)&hbf[(size_t)((bidx << 11) + t1) * 256 + i0];
      bf16x8 av1 =
          *(const bf16x8*)&hbf[(size_t)((bidx << 11) + t1 + 32) * 256 + i0];
      *(bf16x8*)&As[r0 * 72 + kc] = av0;
      *(bf16x8*)&As[(r0 + 32) * 72 + kc] = av1;
      *(bf16x8*)&Bs[r0 * 72 + kc] =
          *(const bf16x8*)&Bcv[(size_t)(n0 + r0) * 768 + k0 + kc];
      *(bf16x8*)&Bs[(r0 + 32) * 72 + kc] =
          *(const bf16x8*)&Bcv[(size_t)(n0 + r0 + 32) * 768 + k0 + kc];
      __syncthreads();
      #pragma unroll
      for (int kk = 0; kk < 64; kk += 32) {
        bf16x8 a0 = *(const bf16x8*)&As[(wr + l15) * 72 + kk + lk];
        bf16x8 a1 = *(const bf16x8*)&As[(wr + 16 + l15) * 72 + kk + lk];
        bf16x8 b0 = *(const bf16x8*)&Bs[(wc + l15) * 72 + kk + lk];
        bf16x8 b1 = *(const bf16x8*)&Bs[(wc + 16 + l15) * 72 + kk + lk];
        acc[0][0] = __builtin_amdgcn_mfma_f32_16x16x32_bf16(a0, b0, acc[0][0], 0, 0, 0);
        acc[0][1] = __builtin_amdgcn_mfma_f32_16x16x32_bf16(a0, b1, acc[0][1], 0, 0, 0);
        acc[1][0] = __builtin_amdgcn_mfma_f32_16x16x32_bf16(a1, b0, acc[1][0], 0, 0, 0);
        acc[1][1] = __builtin_amdgcn_mfma_f32_16x16x32_bf16(a1, b1, acc[1][1], 0, 0, 0);
      }
      __syncthreads();
    }
    int rowb = m0 + wr + (lane >> 4) * 4;
    #pragma unroll
    for (int mi = 0; mi < 2; ++mi)
      #pragma unroll
      for (int ni = 0; ni < 2; ++ni) {
        int gc = n0 + wc + ni * 16 + l15;
        float bias = cb[gc];
        #pragma unroll
        for (int r = 0; r < 4; ++r) {
          float v = acc[mi][ni][r] + bias;
          float g = 0.5f * v * (1.0f + erff(v * 0.70710678118654752440f));
          hconv[(size_t)(rowb + mi * 16 + r) * 256 + gc] = g;
        }
      }
    return;
  }
  // ---- in_proj branch: 64x128 tile, writes xin/z as bf16 ----
  int bid = blk - 512;
  int m0 = (bid & 127) * 64, ny = bid >> 7;
  int n0 = ny * 128;
  int wc = wid * 32;
  f32x4 acc[4][2] = {};
  for (int k0 = 0; k0 < 256; k0 += 64) {
    *(bf16x8*)&As[r0 * 72 + kc] =
        *(const bf16x8*)&hbf[(size_t)(m0 + r0) * 256 + k0 + kc];
    *(bf16x8*)&As[(r0 + 32) * 72 + kc] =
        *(const bf16x8*)&hbf[(size_t)(m0 + r0 + 32) * 256 + k0 + kc];
    #pragma unroll
    for (int rr = 0; rr < 4; ++rr)
      *(bf16x8*)&Bs[(r0 + rr * 32) * 72 + kc] =
          *(const bf16x8*)&Bin[(size_t)(n0 + r0 + rr * 32) * 256 + k0 + kc];
    __syncthreads();
    #pragma unroll
    for (int kk = 0; kk < 64; kk += 32) {
      bf16x8 b0 = *(const bf16x8*)&Bs[(wc + l15) * 72 + kk + lk];
      bf16x8 b1 = *(const bf16x8*)&Bs[(wc + 16 + l15) * 72 + kk + lk];
      #pragma unroll
      for (int q = 0; q < 4; ++q) {
        bf16x8 a = *(const bf16x8*)&As[(q * 16 + l15) * 72 + kk + lk];
        acc[q][0] = __builtin_amdgcn_mfma_f32_16x16x32_bf16(a, b0, acc[q][0], 0, 0, 0);
        acc[q][1] = __builtin_amdgcn_mfma_f32_16x16x32_bf16(a, b1, acc[q][1], 0, 0, 0);
      }
    }
    __syncthreads();
  }
  u16* dst = (ny < 4) ? xin : z;
  int nb = n0 & 511;
  int rsub = (lane >> 4) * 4;
  #pragma unroll
  for (int q = 0; q < 4; ++q)
    #pragma unroll
    for (int ni = 0; ni < 2; ++ni) {
      int gc = nb + wc + ni * 16 + l15;
      #pragma unroll
      for (int r = 0; r < 4; ++r)
        dst[(size_t)(m0 + q * 16 + rsub + r) * 512 + gc] = f2bf(acc[q][ni][r]);
    }
}

// out_proj + combine: out = x + 0.5*(y_bf @ Wt_out_bf^T) + 0.5*hconv
__global__ __launch_bounds__(256) void k_bgemm_outproj(
    const u16* __restrict__ Abf, const u16* __restrict__ Bbf,
    const float* __restrict__ x, const float* __restrict__ hconv,
    float* __restrict__ out) {
  __shared__ __align__(16) u16 As[64 * 72];
  __shared__ __align__(16) u16 Bs[64 * 72];
  int tid = threadIdx.x;
  int m0 = blockIdx.x * 64, n0 = blockIdx.y * 64;
  int lane = tid & 63, wid = tid >> 6;
  int wr = (wid >> 1) * 32, wc = (wid & 1) * 32;
  int l15 = lane & 15, lk = (lane >> 4) * 8;
  int r0 = tid >> 3, kc = (tid & 7) * 8;
  f32x4 acc[2][2] = {};
  for (int k0 = 0; k0 < 512; k0 += 64) {
    *(bf16x8*)&As[r0 * 72 + kc] =
        *(const bf16x8*)&Abf[(size_t)(m0 + r0) * 512 + k0 + kc];
    *(bf16x8*)&As[(r0 + 32) * 72 + kc] =
        *(const bf16x8*)&Abf[(size_t)(m0 + r0 + 32) * 512 + k0 + kc];
    *(bf16x8*)&Bs[r0 * 72 + kc] =
        *(const bf16x8*)&Bbf[(size_t)(n0 + r0) * 512 + k0 + kc];
    *(bf16x8*)&Bs[(r0 + 32) * 72 + kc] =
        *(const bf16x8*)&Bbf[(size_t)(n0 + r0 + 32) * 512 + k0 + kc];
    __syncthreads();
    #pragma unroll
    for (int kk = 0; kk < 64; kk += 32) {
      bf16x8 a0 = *(const bf16x8*)&As[(wr + l15) * 72 + kk + lk];
      bf16x8 a1 = *(const bf16x8*)&As[(wr + 16 + l15) * 72 + kk + lk];
      bf16x8 b0 = *(const bf16x8*)&Bs[(wc + l15) * 72 + kk + lk];
      bf16x8 b1 = *(const bf16x8*)&Bs[(wc + 16 + l15) * 72 + kk + lk];
      acc[0][0] = __builtin_amdgcn_mfma_f32_16x16x32_bf16(a0, b0, acc[0][0], 0, 0, 0);
      acc[0][1] = __builtin_amdgcn_mfma_f32_16x16x32_bf16(a0, b1, acc[0][1], 0, 0, 0);
      acc[1][0] = __builtin_amdgcn_mfma_f32_16x16x32_bf16(a1, b0, acc[1][0], 0, 0, 0);
      acc[1][1] = __builtin_amdgcn_mfma_f32_16x16x32_bf16(a1, b1, acc[1][1], 0, 0, 0);
    }
    __syncthreads();
  }
  int rowb = m0 + wr + (lane >> 4) * 4;
  #pragma unroll
  for (int mi = 0; mi < 2; ++mi)
    #pragma unroll
    for (int ni = 0; ni < 2; ++ni) {
      int gc = n0 + wc + ni * 16 + l15;
      #pragma unroll
      for (int r = 0; r < 4; ++r) {
        size_t off = (size_t)(rowb + mi * 16 + r) * 256 + gc;
        out[off] = x[off] + 0.5f * acc[mi][ni][r] + 0.5f * hconv[off];
      }
    }
}

// x_proj K-split phase 1: Cpart[kc][8192][48] over K-chunk [kc*128, kc*128+128).
__global__ __launch_bounds__(256) void k_xproj_part(
    const float* __restrict__ A, const float* __restrict__ Bt,
    float* __restrict__ Cpart) {
  __shared__ float As[16][68];
  __shared__ float Bs[16][68];
  int tid = threadIdx.x;
  int m0 = blockIdx.x * 64;
  int kc = blockIdx.y;                      // 0..3
  int ar = tid >> 2, ac = (tid & 3) * 4;
  int br = tid >> 4, bc = (tid & 15) * 4;
  int tx = tid & 15, ty = tid >> 4;
  float acc[4][4] = {};
  for (int k0 = kc * 128; k0 < kc * 128 + 128; k0 += 16) {
    float4 av = *reinterpret_cast<const float4*>(A + (size_t)(m0 + ar) * 512 + k0 + ac);
    As[ac + 0][ar] = av.x; As[ac + 1][ar] = av.y;
    As[ac + 2][ar] = av.z; As[ac + 3][ar] = av.w;
    float4 bv = make_float4(0.f, 0.f, 0.f, 0.f);
    if (bc < 48)
      bv = *reinterpret_cast<const float4*>(Bt + (size_t)(k0 + br) * 48 + bc);
    *reinterpret_cast<float4*>(&Bs[br][bc]) = bv;
    __syncthreads();
    #pragma unroll
    for (int kt = 0; kt < 16; ++kt) {
      float4 a = *reinterpret_cast<const float4*>(&As[kt][ty * 4]);
      float4 b = *reinterpret_cast<const float4*>(&Bs[kt][tx * 4]);
      acc[0][0]+=a.x*b.x; acc[0][1]+=a.x*b.y; acc[0][2]+=a.x*b.z; acc[0][3]+=a.x*b.w;
      acc[1][0]+=a.y*b.x; acc[1][1]+=a.y*b.y; acc[1][2]+=a.y*b.z; acc[1][3]+=a.y*b.w;
      acc[2][0]+=a.z*b.x; acc[2][1]+=a.z*b.y; acc[2][2]+=a.z*b.z; acc[2][3]+=a.z*b.w;
      acc[3][0]+=a.w*b.x; acc[3][1]+=a.w*b.y; acc[3][2]+=a.w*b.z; acc[3][3]+=a.w*b.w;
    }
    __syncthreads();
  }
  float* C = Cpart + (size_t)kc * (MROWS * 48);
  if (tx < 12) {
    #pragma unroll
    for (int i = 0; i < 4; ++i) {
      float4 cv = make_float4(acc[i][0], acc[i][1], acc[i][2], acc[i][3]);
      *reinterpret_cast<float4*>(C + (size_t)(m0 + ty * 4 + i) * 48 + tx * 4) = cv;
    }
  }
}

// dt_proj (+ fused partial-sum): 2048 blocks x 4 rows. Threads 0..191 sum the
// 4 K-split partials (same (((p0+p1)+p2)+p3) order as the old sum kernel),
// write xdbl, stash dt cols in LDS. Then softplus(dt@Wdt+db) as before.
__global__ __launch_bounds__(256) void k_dtproj(
    const float* __restrict__ Cpart, const float* __restrict__ Wdt,
    const float* __restrict__ db, float* __restrict__ xdbl,
    float* __restrict__ delta) {
  __shared__ float dts[4][17];
  int tid = threadIdx.x;
  int m0 = blockIdx.x * 4;
  const size_t S = (size_t)MROWS * 48;
  if (tid < 192) {
    int rr = tid / 48, cc = tid - rr * 48;
    size_t off = (size_t)(m0 + rr) * 48 + cc;
    float v = ((Cpart[off] + Cpart[S + off]) + Cpart[2 * S + off]) + Cpart[3 * S + off];
    xdbl[off] = v;
    if (cc < 16) dts[rr][cc] = v;
  }
  __syncthreads();
  float wv0[16], wv1[16];
  #pragma unroll
  for (int r = 0; r < 16; ++r) {
    wv0[r] = Wdt[r * 512 + tid];
    wv1[r] = Wdt[r * 512 + tid + 256];
  }
  float b0 = db[tid], b1 = db[tid + 256];
  #pragma unroll
  for (int m = 0; m < 4; ++m) {
    float a0 = b0, a1 = b1;
    #pragma unroll
    for (int r = 0; r < 16; ++r) {
      float d = dts[m][r];
      a0 += d * wv0[r];
      a1 += d * wv1[r];
    }
    delta[(size_t)(m0 + m) * 512 + tid]       = (a0 > 20.0f) ? a0 : log1pf(__expf(a0));
    delta[(size_t)(m0 + m) * 512 + tid + 256] = (a1 > 20.0f) ? a1 : log1pf(__expf(a1));
  }
}

// ---------------- depthwise causal conv (DCONV=4) + SiLU; bf16 input ---------
__global__ __launch_bounds__(256) void k_dwconv(
    const u16* __restrict__ xin, const float* __restrict__ cw,
    const float* __restrict__ cb, float* __restrict__ xc) {
  int idx = blockIdx.x * 256 + threadIdx.x;
  int di = idx & 511;
  int m  = idx >> 9;
  int t  = m & 2047;
  float w0 = cw[di * 4 + 0], w1 = cw[di * 4 + 1];
  float w2 = cw[di * 4 + 2], w3 = cw[di * 4 + 3];
  const u16* base = xin + (size_t)m * 512 + di;
  float acc = cb[di] + w3 * bf2f(base[0]);
  if (t >= 1) acc += w2 * bf2f(base[-512]);
  if (t >= 2) acc += w1 * bf2f(base[-1024]);
  if (t >= 3) acc += w0 * bf2f(base[-1536]);
  xc[(size_t)m * 512 + di] = silu_f(acc);
}

// ---------------- chunked scan: thread-per-(b,chunk,di), 16 states in regs --
__global__ __launch_bounds__(256) void k_scan1(
    const float* __restrict__ delta, const float* __restrict__ xdbl,
    const float* __restrict__ xc, const float* __restrict__ Alog,
    float* __restrict__ Aagg, float* __restrict__ Bagg) {
  int di = ((blockIdx.x & 1) << 8) | threadIdx.x;
  int c  = (blockIdx.x >> 1) & 63;
  int b  = blockIdx.x >> 7;
  float nA[16];
  #pragma unroll
  for (int q = 0; q < 4; ++q) {
    float4 v = *reinterpret_cast<const float4*>(Alog + (size_t)di * 16 + q * 4);
    nA[q*4+0] = -__expf(v.x); nA[q*4+1] = -__expf(v.y);
    nA[q*4+2] = -__expf(v.z); nA[q*4+3] = -__expf(v.w);
  }
  float ap[16], bacc[16];
  #pragma unroll
  for (int s = 0; s < 16; ++s) { ap[s] = 1.0f; bacc[s] = 0.0f; }
  int row0 = b * 2048 + c * LCHUNK;
  const float* dp = delta + (size_t)row0 * 512 + di;
  const float* xp = xc    + (size_t)row0 * 512 + di;
  const float* Bp = xdbl  + (size_t)row0 * 48 + 16;
  #pragma unroll 2
  for (int t = 0; t < LCHUNK; ++t) {
    float dv = dp[t * 512];
    float u  = dv * xp[t * 512];
    #pragma unroll
    for (int s = 0; s < 16; ++s) {
      float e = __expf(dv * nA[s]);
      ap[s]   *= e;
      bacc[s]  = e * bacc[s] + u * Bp[t * 48 + s];
    }
  }
  size_t base = ((size_t)((b * 64 + c) * 16)) * 512 + di;
  #pragma unroll
  for (int s = 0; s < 16; ++s) {
    Aagg[base + (size_t)s * 512] = ap[s];
    Bagg[base + (size_t)s * 512] = bacc[s];
  }
}

__global__ __launch_bounds__(256) void k_scan2(
    const float* __restrict__ Aagg, const float* __restrict__ Bagg,
    float* __restrict__ Hinit) {
  int g  = blockIdx.x * 256 + threadIdx.x;
  int di = g & 511, s = (g >> 9) & 15, b = g >> 13;
  float h = 0.0f;
  for (int c = 0; c < NCHUNK; ++c) {
    size_t idx = ((size_t)((b * 64 + c) * 16 + s)) * 512 + di;
    float a = Aagg[idx], bb = Bagg[idx];
    Hinit[idx] = h;
    h = a * h + bb;
  }
}

// pass 3: re-scan; fused y = (scan + xc*D) * silu(z); bf16 z input, bf16 y out
__global__ __launch_bounds__(256) void k_scan3(
    const float* __restrict__ delta, const float* __restrict__ xdbl,
    const float* __restrict__ xc, const u16* __restrict__ z,
    const float* __restrict__ Alog, const float* __restrict__ Dp,
    const float* __restrict__ Hinit, u16* __restrict__ y) {
  int di = ((blockIdx.x & 1) << 8) | threadIdx.x;
  int c  = (blockIdx.x >> 1) & 63;
  int b  = blockIdx.x >> 7;
  float nA[16];
  #pragma unroll
  for (int q = 0; q < 4; ++q) {
    float4 v = *reinterpret_cast<const float4*>(Alog + (size_t)di * 16 + q * 4);
    nA[q*4+0] = -__expf(v.x); nA[q*4+1] = -__expf(v.y);
    nA[q*4+2] = -__expf(v.z); nA[q*4+3] = -__expf(v.w);
  }
  float h[16];
  size_t hb = ((size_t)((b * 64 + c) * 16)) * 512 + di;
  #pragma unroll
  for (int s = 0; s < 16; ++s) h[s] = Hinit[hb + (size_t)s * 512];
  float Dv = Dp[di];
  int row0 = b * 2048 + c * LCHUNK;
  const float* dp = delta + (size_t)row0 * 512 + di;
  const float* xp = xc    + (size_t)row0 * 512 + di;
  const u16*   zp = z     + (size_t)row0 * 512 + di;
  const float* Bp = xdbl  + (size_t)row0 * 48 + 16;
  const float* Cp = xdbl  + (size_t)row0 * 48 + 32;
  u16* yp         = y     + (size_t)row0 * 512 + di;
  #pragma unroll 2
  for (int t = 0; t < LCHUNK; ++t) {
    float dv  = dp[t * 512];
    float xcv = xp[t * 512];
    float u   = dv * xcv;
    float yv  = 0.0f;
    #pragma unroll
    for (int s = 0; s < 16; ++s) {
      float e = __expf(dv * nA[s]);
      h[s] = e * h[s] + u * Bp[t * 48 + s];
      yv  += h[s] * Cp[t * 48 + s];
    }
    yv += xcv * Dv;
    float zv = bf2f(zp[t * 512]);
    yp[t * 512] = f2bf(yv * silu_f(zv));
  }
}

// ---------------- host launcher ---------------------------------------------
extern "C" void kernel_launch(void* const* d_in, const int* in_sizes, int n_in,
                              void* d_out, int out_size, void* d_ws, size_t ws_size,
                              hipStream_t stream) {
  const float* x     = (const float*)d_in[0];
  const float* lnw   = (const float*)d_in[1];
  const float* lnb   = (const float*)d_in[2];
  const float* convw = (const float*)d_in[3];
  const float* convb = (const float*)d_in[4];
  const float* inw   = (const float*)d_in[5];
  const float* c1w   = (const float*)d_in[6];
  const float* c1b   = (const float*)d_in[7];
  const float* xw    = (const float*)d_in[8];
  const float* dtw   = (const float*)d_in[9];
  const float* dtb   = (const float*)d_in[10];
  const float* alog  = (const float*)d_in[11];
  const float* Dp    = (const float*)d_in[12];
  const float* ow    = (const float*)d_in[13];
  float* ws  = (float*)d_ws;
  float* out = (float*)d_out;

  u16* hbf     = (u16*)(ws + OFF_HBF);
  float* hconv = ws + OFF_HCONV;
  u16* xinbf   = (u16*)(ws + OFF_XIN);
  float* xpart = ws + OFF_XPART;
  u16* zbf     = (u16*)(ws + OFF_Z);
  float* xc    = ws + OFF_XC;
  float* delta = ws + OFF_DELTA;
  float* xdbl  = ws + OFF_XDBL;
  u16* ybf     = (u16*)(ws + OFF_YBF);
  float* Aagg  = ws + OFF_AAGG;
  float* Bagg  = ws + OFF_BAGG;
  float* Hinit = ws + OFF_HINIT;
  u16* winbf   = (u16*)(ws + OFF_WTINBF);
  u16* wcvbf   = (u16*)(ws + OFF_WTCVBF);
  u16* woutbf  = (u16*)(ws + OFF_WTOUTBF);
  float* Wtx   = ws + OFF_WTX;
  float* Wtdt  = ws + OFF_WTDT;

  k_ln_repack<<<4480, 256, 0, stream>>>(x, lnw, lnb, hbf,
                                        inw, convw, xw, dtw, ow, ws);
  k_bgemm_both<<<1536, 256, 0, stream>>>(hbf, wcvbf, convb, hconv,
                                         winbf, xinbf, zbf);
  k_dwconv<<<16384, 256, 0, stream>>>(xinbf, c1w, c1b, xc);
  k_xproj_part<<<dim3(128, 4), 256, 0, stream>>>(xc, Wtx, xpart);
  k_dtproj<<<2048, 256, 0, stream>>>(xpart, Wtdt, dtb, xdbl, delta);
  k_scan1<<<512, 256, 0, stream>>>(delta, xdbl, xc, alog, Aagg, Bagg);
  k_scan2<<<128, 256, 0, stream>>>(Aagg, Bagg, Hinit);
  k_scan3<<<512, 256, 0, stream>>>(delta, xdbl, xc, zbf, alog, Dp, Hinit, ybf);
  k_bgemm_outproj<<<dim3(128, 4), 256, 0, stream>>>(ybf, woutbf, x, hconv, out);
}